// Round 3
// baseline (261.779 us; speedup 1.0000x reference)
//
#include <hip/hip_runtime.h>

// OFT rotation, bf16-MFMA, barrier-free apply.
// out[n, r*64+c] = sum_k x[n, r*64+k] * R[r][k][c]
// R = I + 2Q + 2*Q^2*(I + Q + Q^2)  (2 matmuls, 5-term Neumann)
// build_R emits R^T (layout [c][k]) in bf16 so apply's MFMA B-fragment is a
// contiguous 16B LDS read.

#define LDP 68   // fp32 LDS row stride in build_R

typedef __attribute__((ext_vector_type(8))) short short8;   // 8 bf16 = 4 VGPR
typedef __attribute__((ext_vector_type(4))) float f32x4;

static __device__ __forceinline__ unsigned short f2bf(float f) {
  unsigned u = __float_as_uint(f);
  u += 0x7FFF + ((u >> 16) & 1);   // round-to-nearest-even
  return (unsigned short)(u >> 16);
}

static __device__ __forceinline__ short8 pack8(float4 a, float4 b) {
  short8 s;
  s[0] = (short)f2bf(a.x); s[1] = (short)f2bf(a.y);
  s[2] = (short)f2bf(a.z); s[3] = (short)f2bf(a.w);
  s[4] = (short)f2bf(b.x); s[5] = (short)f2bf(b.y);
  s[6] = (short)f2bf(b.z); s[7] = (short)f2bf(b.w);
  return s;
}

// p += A[r0..r0+3][:] * B[:][c0..c0+3], K=64, row stride LDP
__device__ __forceinline__ void mm_tile_68(const float (*A)[LDP], const float (*Bm)[LDP],
                                           int r0, int c0, float p[4][4]) {
  for (int k = 0; k < 64; k += 4) {
    float4 bv[4], av[4];
#pragma unroll
    for (int u = 0; u < 4; ++u) bv[u] = *(const float4*)&Bm[k + u][c0];
#pragma unroll
    for (int i = 0; i < 4; ++i) av[i] = *(const float4*)&A[r0 + i][k];
#pragma unroll
    for (int u = 0; u < 4; ++u) {
      const float4 b = bv[u];
#pragma unroll
      for (int i = 0; i < 4; ++i) {
        const float a = ((const float*)&av[i])[u];
        p[i][0] += a * b.x;
        p[i][1] += a * b.y;
        p[i][2] += a * b.z;
        p[i][3] += a * b.w;
      }
    }
  }
}

// ---------------- Kernel 1: build R^T (bf16), one block per rotation block ---------

__global__ __launch_bounds__(256) void oft_build_R(const float* __restrict__ w,
                                                   unsigned* __restrict__ RT) {
  const int r = blockIdx.x;
  const int t = threadIdx.x;
  __shared__ float Q[64][LDP];
  __shared__ float P[64][LDP];
  __shared__ float T[64][LDP];

  for (int f = t; f < 64 * LDP; f += 256) (&Q[0][0])[f] = 0.f;
  __syncthreads();

  for (int i = t; i < 2016; i += 256) {
    int row = 0, rem = i;
    while (rem >= 63 - row) { rem -= 63 - row; ++row; }
    const int col = row + 1 + rem;
    const float v = w[r * 2016 + i];
    Q[row][col] = v;
    Q[col][row] = -v;
  }
  __syncthreads();

  const int r0 = (t >> 4) * 4, c0 = (t & 15) * 4;

  // P = Q*Q ;  T = I + Q + P
  float p[4][4] = {};
  mm_tile_68(Q, Q, r0, c0, p);
#pragma unroll
  for (int i = 0; i < 4; ++i)
#pragma unroll
    for (int j = 0; j < 4; ++j) {
      P[r0 + i][c0 + j] = p[i][j];
      T[r0 + i][c0 + j] = p[i][j] + Q[r0 + i][c0 + j] + ((r0 + i) == (c0 + j) ? 1.f : 0.f);
    }
  __syncthreads();

  // R = I + 2Q + 2*(P*T)
  float p2[4][4] = {};
  mm_tile_68(P, T, r0, c0, p2);
  float acc[4][4];
#pragma unroll
  for (int i = 0; i < 4; ++i)
#pragma unroll
    for (int j = 0; j < 4; ++j)
      acc[i][j] = ((r0 + i) == (c0 + j) ? 1.f : 0.f)
                + 2.f * Q[r0 + i][c0 + j] + 2.f * p2[i][j];
  __syncthreads();

  // transpose into T:  T[c][k] = R[k][c]
#pragma unroll
  for (int i = 0; i < 4; ++i)
#pragma unroll
    for (int j = 0; j < 4; ++j)
      T[c0 + j][r0 + i] = acc[i][j];
  __syncthreads();

#pragma unroll
  for (int i2 = 0; i2 < 8; ++i2) {
    const int f = t + 256 * i2;          // uint index, 2048 per block
    const int row = f >> 5, col = (f & 31) * 2;
    unsigned lo = f2bf(T[row][col]);
    unsigned hi = f2bf(T[row][col + 1]);
    RT[(size_t)r * 2048 + f] = lo | (hi << 16);
  }
}

// ---------------- Kernel 2: barrier-free apply, global->reg fragments --------------

#define WAVES 4
#define TILES 4   // 16-row tiles per wave; wg covers 4*4*16 = 256 rows

__global__ __launch_bounds__(256) void oft_apply(const float* __restrict__ x,
                                                 const unsigned* __restrict__ RT,
                                                 float* __restrict__ out) {
  const int r = blockIdx.x;          // rotation block 0..63
  const int t = threadIdx.x;

  // +8 bf16 pad -> row stride 144 B: b128 frag reads conflict-free
  __shared__ __align__(16) unsigned short Rs[64][72];
  {
    const uint4* Rg = (const uint4*)(RT + (size_t)r * 2048);
    uint4 v0 = Rg[t];
    uint4 v1 = Rg[t + 256];
    *(uint4*)&Rs[t >> 3][(t & 7) * 8] = v0;
    *(uint4*)&Rs[(t + 256) >> 3][((t + 256) & 7) * 8] = v1;
  }
  __syncthreads();

  const int lane = t & 63, w = t >> 6;
  const int lo = lane & 15, q = lane >> 4;

  // B fragments: B[k][n], n = lane&15, k = q*8+j (+32h). R^T row c*16+lo = out col.
  short8 bfr[2][4];
#pragma unroll
  for (int h = 0; h < 2; ++h)
#pragma unroll
    for (int c = 0; c < 4; ++c)
      bfr[h][c] = *(const short8*)&Rs[c * 16 + lo][h * 32 + q * 8];

  const size_t colOff = (size_t)r * 64;
  const int rowBase = blockIdx.y * (WAVES * TILES * 16);
  const size_t tileStride = (size_t)(WAVES * 16) * 4096;   // rows advance by 64

  // A-frag: A[m][k], m = lane&15 (row), k = q*8+j (+32h): per lane 2x16B contiguous
  const float* lp = x + (size_t)(rowBase + w * 16 + lo) * 4096 + colOff + (size_t)q * 8;
  float* sp = out + (size_t)(rowBase + w * 16 + q * 4) * 4096 + colOff + lo;

  float4 L0 = *(const float4*)(lp + 0);
  float4 L1 = *(const float4*)(lp + 4);
  float4 L2 = *(const float4*)(lp + 32);
  float4 L3 = *(const float4*)(lp + 36);

#pragma unroll
  for (int tt = 0; tt < TILES; ++tt) {
    float4 C0 = L0, C1 = L1, C2 = L2, C3 = L3;
    if (tt + 1 < TILES) {   // prefetch next tile while this one computes/stores
      const float* np = lp + (size_t)(tt + 1) * tileStride;
      L0 = *(const float4*)(np + 0);
      L1 = *(const float4*)(np + 4);
      L2 = *(const float4*)(np + 32);
      L3 = *(const float4*)(np + 36);
    }
    short8 a0 = pack8(C0, C1);   // k = q*8..q*8+7
    short8 a1 = pack8(C2, C3);   // k = 32+q*8..

    f32x4 acc[4];
#pragma unroll
    for (int c = 0; c < 4; ++c) { acc[c][0] = 0.f; acc[c][1] = 0.f; acc[c][2] = 0.f; acc[c][3] = 0.f; }
#pragma unroll
    for (int c = 0; c < 4; ++c)
      acc[c] = __builtin_amdgcn_mfma_f32_16x16x32_bf16(a0, bfr[0][c], acc[c], 0, 0, 0);
#pragma unroll
    for (int c = 0; c < 4; ++c)
      acc[c] = __builtin_amdgcn_mfma_f32_16x16x32_bf16(a1, bfr[1][c], acc[c], 0, 0, 0);

    // C/D: col = lane&15, row = q*4 + i
    float* op = sp + (size_t)tt * tileStride;
#pragma unroll
    for (int c = 0; c < 4; ++c)
#pragma unroll
      for (int i = 0; i < 4; ++i)
        __builtin_nontemporal_store(acc[c][i], op + (size_t)i * 4096 + c * 16);
  }
}

extern "C" void kernel_launch(void* const* d_in, const int* in_sizes, int n_in,
                              void* d_out, int out_size, void* d_ws, size_t ws_size,
                              hipStream_t stream) {
  const float* x = (const float*)d_in[0];   // (8192, 4096) fp32
  const float* w = (const float*)d_in[1];   // (64, 2016) fp32
  float* out = (float*)d_out;               // (8192, 4096) fp32
  unsigned* RTws = (unsigned*)d_ws;         // 64 * 2048 uints = 512 KB (bf16 R^T)

  oft_build_R<<<64, 256, 0, stream>>>(w, RTws);
  oft_apply<<<dim3(64, 8192 / (WAVES * TILES * 16)), 256, 0, stream>>>(x, RTws, out);
}